// Round 7
// baseline (395.872 us; speedup 1.0000x reference)
//
#include <hip/hip_runtime.h>
#include <hip/hip_bf16.h>
#include <math.h>

#define NTOK 16384
#define HDIM 1024
#define DSZ 32
#define DGZ 32
#define FMZ 64
#define NEXP 4
#define FFZ 2048

typedef __attribute__((ext_vector_type(4))) float f32x4;
typedef __attribute__((ext_vector_type(8))) short bf16x8;

__device__ __forceinline__ unsigned short f2bf(float f){
    union { float f; unsigned int u; } v; v.f = f;
    unsigned int r = (v.u + 0x7FFFu + ((v.u >> 16) & 1u)) >> 16;
    return (unsigned short)r;
}
__device__ __forceinline__ float gelu_f(float x){
    return 0.5f * x * (1.0f + erff(x * 0.70710678118654752440f));
}
__device__ __forceinline__ void gld_lds16(const void* g, void* s){
    __builtin_amdgcn_global_load_lds((const __attribute__((address_space(1))) unsigned int*)g,
                                     (__attribute__((address_space(3))) unsigned int*)s, 16, 0, 0);
}

// ---------------- kernel 1: per-token LN stats only ----------------
__global__ __launch_bounds__(256) void k_stats(const float* __restrict__ h,
        float* __restrict__ mu_g, float* __restrict__ rs_g){
    int tid = threadIdx.x;
    int wv = tid >> 6, l = tid & 63;
    int tok = blockIdx.x * 4 + wv;
    const float4* hp = (const float4*)(h + (size_t)tok * HDIM);
    float s = 0.f, s2 = 0.f;
    #pragma unroll
    for (int p = 0; p < 4; ++p){
        float4 v = hp[p * 64 + l];
        s  += v.x + v.y + v.z + v.w;
        s2 += v.x*v.x + v.y*v.y + v.z*v.z + v.w*v.w;
    }
    #pragma unroll
    for (int off = 32; off >= 1; off >>= 1){
        s  += __shfl_xor(s,  off, 64);
        s2 += __shfl_xor(s2, off, 64);
    }
    if (l == 0){
        float mu = s * (1.0f / HDIM);
        float var = s2 * (1.0f / HDIM) - mu * mu;
        var = fmaxf(var, 0.f);
        mu_g[tok] = mu;
        rs_g[tok] = 1.0f / sqrtf(var + 1e-5f);
    }
}

// ---------------- kernel 2: transpose + fp32->bf16 (weights, per expert) ----------------
__global__ __launch_bounds__(256) void k_transpose_bf(const float* __restrict__ in,
        unsigned short* __restrict__ out, int R, int C){
    __shared__ float tile[32][33];
    size_t mat = (size_t)blockIdx.z * R * C;
    int bx = blockIdx.x * 32;   // col base
    int by = blockIdx.y * 32;   // row base
    int x = threadIdx.x, y = threadIdx.y;
    const float* ip = in + mat;
    unsigned short* op = out + mat;
    #pragma unroll
    for (int i = 0; i < 32; i += 8)
        tile[y + i][x] = ip[(size_t)(by + y + i) * C + (bx + x)];
    __syncthreads();
    #pragma unroll
    for (int i = 0; i < 32; i += 8)
        op[(size_t)(bx + y + i) * R + (by + x)] = f2bf(tile[x][y + i]);
}

// ---------------- kernel 3: fused fp32 routing (unchanged, verified) ----------------
__global__ __launch_bounds__(256) void k_route(
    const float* __restrict__ h, const float* __restrict__ tok_emb,
    const float* __restrict__ ln_g, const float* __restrict__ ln_b,
    const float* __restrict__ Wg, const float* __restrict__ bg,
    const float* __restrict__ Wf, const float* __restrict__ bfv,
    const float* __restrict__ Wr, const float* __restrict__ br,
    const float* __restrict__ mu_g, const float* __restrict__ rs_g,
    float* __restrict__ tprob, int* __restrict__ list, int* __restrict__ cnt,
    float* __restrict__ imp_part)
{
    __shared__ __align__(16) char smem[62208];
    float* lgs  = (float*)(smem);                      // [1024]
    float* lbs  = (float*)(smem + 4096);               // [1024]
    float (*hsT)[64]  = (float(*)[64])(smem + 8192);   // [64 k][64 tok]
    float (*wgs)[32]  = (float(*)[32])(smem + 24576);  // [64 k][32 c]
    float (*gacc)[32] = (float(*)[32])(smem + 32768);  // [64 tok][32 c]
    float* mus = (float*)(smem + 40960);               // [64]
    float* rss = (float*)(smem + 41216);               // [64]
    float (*wrs)[4]     = (float(*)[4])(smem + 41472); // [64][4]
    float (*logit_s)[5] = (float(*)[5])(smem + 42496);
    float (*prob_s)[5]  = (float(*)[5])(smem + 43776);
    int* lcnt  = (int*)(smem + 45056);
    int* lbase = (int*)(smem + 45072);
    float (*agT)[64] = (float(*)[64])(smem);           // [64 j][64 tok]
    float (*wfs)[64] = (float(*)[64])(smem + 16384);   // [64 k][64 f]
    float (*uT)[64]  = (float(*)[64])(smem + 45824);   // [64 f][64 tok]

    int tid = threadIdx.x;
    int t0 = blockIdx.x * 64;

    ((float4*)lgs)[tid] = ((const float4*)ln_g)[tid];
    ((float4*)lbs)[tid] = ((const float4*)ln_b)[tid];
    if (tid < 64){ mus[tid] = mu_g[t0 + tid]; rss[tid] = rs_g[t0 + tid]; }
    if (tid < 64) ((float4*)wrs)[tid] = ((const float4*)Wr)[tid];
    if (tid < 4) lcnt[tid] = 0;
    __syncthreads();

    int l = tid & 63, w = tid >> 6;
    int tg = l & 7, cg = l >> 3, q = w;
    float g_[8][4];
    #pragma unroll
    for (int i=0;i<8;++i){ g_[i][0]=0.f; g_[i][1]=0.f; g_[i][2]=0.f; g_[i][3]=0.f; }
    int tokrow = tid >> 2;
    float m_ = mus[tokrow], r_ = rss[tokrow];
    const float* hrow = h + (size_t)(t0 + tokrow) * HDIM;

    for (int k0 = 0; k0 < HDIM; k0 += 64){
        #pragma unroll
        for (int p = 0; p < 4; ++p){
            int f4 = (tid & 3) + 4 * p;
            float4 v = ((const float4*)(hrow + k0))[f4];
            int c = f4 * 4;
            hsT[c+0][tokrow] = (v.x - m_) * r_ * lgs[k0+c+0] + lbs[k0+c+0];
            hsT[c+1][tokrow] = (v.y - m_) * r_ * lgs[k0+c+1] + lbs[k0+c+1];
            hsT[c+2][tokrow] = (v.z - m_) * r_ * lgs[k0+c+2] + lbs[k0+c+2];
            hsT[c+3][tokrow] = (v.w - m_) * r_ * lgs[k0+c+3] + lbs[k0+c+3];
        }
        {
            int wgrow = tid >> 2;
            #pragma unroll
            for (int p = 0; p < 2; ++p){
                int f4 = (tid & 3) + 4 * p;
                ((float4*)wgs[wgrow])[f4] = ((const float4*)(Wg + (size_t)(k0 + wgrow) * DGZ))[f4];
            }
        }
        __syncthreads();
        #pragma unroll
        for (int kk16 = 0; kk16 < 16; ++kk16){
            int kk = q * 16 + kk16;
            float4 a0 = ((float4*)hsT[kk])[tg*2];
            float4 a1 = ((float4*)hsT[kk])[tg*2+1];
            float4 wv = ((float4*)wgs[kk])[cg];
            float av[8] = {a0.x,a0.y,a0.z,a0.w,a1.x,a1.y,a1.z,a1.w};
            float wj[4] = {wv.x,wv.y,wv.z,wv.w};
            #pragma unroll
            for (int i=0;i<8;++i){
                g_[i][0] += av[i]*wj[0]; g_[i][1] += av[i]*wj[1];
                g_[i][2] += av[i]*wj[2]; g_[i][3] += av[i]*wj[3];
            }
        }
        __syncthreads();
    }
    for (int qq = 0; qq < 4; ++qq){
        if (w == qq){
            #pragma unroll
            for (int i=0;i<8;++i){
                int tok = tg*8+i;
                #pragma unroll
                for (int j=0;j<4;++j){
                    int c = cg*4+j;
                    if (qq == 0) gacc[tok][c] = g_[i][j];
                    else gacc[tok][c] += g_[i][j];
                }
            }
        }
        __syncthreads();
    }
    {
        int tokr = tid >> 2;
        #pragma unroll
        for (int p = 0; p < 2; ++p){
            int f4 = (tid & 3) + 4*p;
            float4 v = ((const float4*)(tok_emb + (size_t)(t0 + tokr) * DSZ))[f4];
            int j = f4 * 4;
            agT[j+0][tokr] = v.x; agT[j+1][tokr] = v.y;
            agT[j+2][tokr] = v.z; agT[j+3][tokr] = v.w;
        }
        int c = tid & 31, tok8 = (tid >> 5) * 8;
        float bgc = bg[c];
        #pragma unroll
        for (int i=0;i<8;++i){
            int tok = tok8 + i;
            agT[32 + c][tok] = gelu_f(gacc[tok][c] + bgc);
        }
        int row = tid >> 2;
        #pragma unroll
        for (int p = 0; p < 4; ++p){
            int f4 = (tid & 3) + 4*p;
            ((float4*)wfs[row])[f4] = ((const float4*)(Wf + (size_t)row * FMZ))[f4];
        }
    }
    __syncthreads();
    {
        int tok = tid & 63, fq = tid >> 6;
        float u_[16];
        #pragma unroll
        for (int i=0;i<16;++i) u_[i]=0.f;
        for (int j = 0; j < 64; ++j){
            float a = agT[j][tok];
            float wv[16];
            *(float4*)&wv[0]  = ((float4*)wfs[j])[fq*4+0];
            *(float4*)&wv[4]  = ((float4*)wfs[j])[fq*4+1];
            *(float4*)&wv[8]  = ((float4*)wfs[j])[fq*4+2];
            *(float4*)&wv[12] = ((float4*)wfs[j])[fq*4+3];
            #pragma unroll
            for (int i=0;i<16;++i) u_[i] += a * wv[i];
        }
        #pragma unroll
        for (int i=0;i<16;++i){
            int f = fq*16+i;
            uT[f][tok] = gelu_f(u_[i] + bfv[f]);
        }
    }
    __syncthreads();
    {
        int tok = tid & 63, e = tid >> 6;
        float lt = 0.f;
        #pragma unroll 8
        for (int f = 0; f < 64; ++f) lt += uT[f][tok] * wrs[f][e];
        logit_s[tok][e] = lt + br[e];
    }
    __syncthreads();
    int my_e = 0, my_pos = 0;
    if (tid < 64){
        int tok = tid;
        float l0 = logit_s[tok][0], l1 = logit_s[tok][1];
        float l2 = logit_s[tok][2], l3 = logit_s[tok][3];
        float mx = fmaxf(fmaxf(l0,l1), fmaxf(l2,l3));
        float p0 = expf(l0-mx), p1 = expf(l1-mx), p2 = expf(l2-mx), p3 = expf(l3-mx);
        float inv = 1.0f / (p0+p1+p2+p3);
        int be = 0; float bp = p0;
        if (p1 > bp){ bp = p1; be = 1; }
        if (p2 > bp){ bp = p2; be = 2; }
        if (p3 > bp){ bp = p3; be = 3; }
        tprob[t0 + tok] = bp * inv;
        prob_s[tok][0] = p0*inv; prob_s[tok][1] = p1*inv;
        prob_s[tok][2] = p2*inv; prob_s[tok][3] = p3*inv;
        my_e = be;
        my_pos = atomicAdd(&lcnt[be], 1);
    }
    __syncthreads();
    if (tid < 4) lbase[tid] = atomicAdd(&cnt[tid], lcnt[tid]);
    __syncthreads();
    if (tid < 64) list[my_e * NTOK + lbase[my_e] + my_pos] = t0 + tid;
    if (tid < 4){
        float s = 0.f;
        for (int t = 0; t < 64; ++t) s += prob_s[t][tid];
        imp_part[blockIdx.x * 4 + tid] = s;
    }
}

// ---------------- kernel 3b: pack h rows into routing order (fp32 -> bf16) ----------------
__global__ __launch_bounds__(256) void k_pack(const float* __restrict__ h,
        const int* __restrict__ list, const int* __restrict__ cnt,
        unsigned short* __restrict__ Ap){
    int wv = threadIdx.x >> 6, l = threadIdx.x & 63;
    int p = blockIdx.x * 4 + wv;
    int b1 = cnt[0], b2 = b1 + cnt[1], b3 = b2 + cnt[2];
    int e, g;
    if (p < b1){ e = 0; g = p; }
    else if (p < b2){ e = 1; g = p - b1; }
    else if (p < b3){ e = 2; g = p - b2; }
    else { e = 3; g = p - b3; }
    int tok = list[e * NTOK + g];
    const float4* src = (const float4*)(h + (size_t)tok * HDIM);
    ushort4* dst = (ushort4*)(Ap + (size_t)p * HDIM);
    #pragma unroll
    for (int i = 0; i < 4; ++i){
        float4 v = src[l + 64 * i];
        ushort4 o; o.x = f2bf(v.x); o.y = f2bf(v.y); o.z = f2bf(v.z); o.w = f2bf(v.w);
        dst[l + 64 * i] = o;
    }
}

// ---------------- grouped GEMM v5: 256x256, K-complete quadrant phases (m201 port) ----------------
// 512 thr = 8 waves (2M x 4N), per-wave C = 128x64. BK=64 full-K per phase.
// LDS 128 KiB: A [2 buf][2 mhalf][128][64]bf16 @0; B [2 buf][2 nhalf][128][64] @65536.
// Per tile t (buf CB), 4 phases = m-pair quadrants; 8 B-frags ds-read ONCE at P0, held in regs.
// Stage plan: P0: A-h0(t+1)->CBo, P1: A-h1(t+1)->CBo + B-h0(t+2)->CB, P2: B-h1(t+2)->CB.
//   (B region of CB is dead after P0's reads; A(t+1) goes to the other buffer. Overwrite-safe.)
// ONE counted vmcnt(4) per tile at P3 end: retires A(t+1)+B(t+1), leaves B(t+2)'s 4 loads in flight.
// Swizzle (verified 0-conflict): stored chunk s of row r holds global chunk s^(r&7);
//   source pre-swizzled (gld_lds dest linear), read XORs chunk with l&7.
// XCD chunked swizzle: physical f -> logical g=(j>>2)*32+(f&7)*4+(j&3), j=f>>3; nn=g%GX, mm=g/GX.
template<int KTD, int NT, bool PH1>
__global__ __launch_bounds__(512, 2) void k_gemm256(
    const unsigned short* __restrict__ Abase,
    const unsigned short* __restrict__ Bbase,
    const int* __restrict__ list, const int* __restrict__ cnt_g,
    const float* __restrict__ bias,
    unsigned short* __restrict__ A1out,
    const float* __restrict__ hres,
    const float* __restrict__ tprob,
    float* __restrict__ outp)
{
    constexpr int NKT = KTD / 64;
    constexpr int NKTm1 = NKT - 1;
    constexpr int GX = NT / 256;               // 8 (PH1) or 4 (PH2), pow2
    __shared__ __align__(16) char lds[131072];
    int e = blockIdx.z;
    int cnt = cnt_g[e];
    int pb = 0;
    #pragma unroll
    for (int i = 0; i < 3; ++i) if (i < e) pb += cnt_g[i];

    // XCD chunked swizzle (NWG = GX*64, %32==0)
    int f = blockIdx.y * GX + blockIdx.x;
    int jj = f >> 3, xk = f & 7;
    int g = (jj >> 2) * 32 + xk * 4 + (jj & 3);
    int m0 = (g / GX) * 256;
    int n0 = (g & (GX - 1)) * 256;
    if (m0 >= cnt) return;

    int tid = threadIdx.x, w = tid >> 6, l = tid & 63;
    int wr = w >> 2, wc = w & 3;

    // staging sources: line hl = half*2 + line; row = half*128 + line*64 + (tid>>3)
    int srow = tid >> 3;
    int jsrc = ((tid & 7) ^ (srow & 7)) * 8;
    const unsigned short* aS[4];
    const unsigned short* bS[4];
    #pragma unroll
    for (int hl = 0; hl < 4; ++hl){
        int row = (hl >> 1) * 128 + (hl & 1) * 64 + srow;
        int ga = m0 + row; if (ga > cnt - 1) ga = cnt - 1;
        aS[hl] = Abase + (size_t)(pb + ga) * KTD + jsrc;
        bS[hl] = Bbase + ((size_t)e * NT + n0 + row) * KTD + jsrc;
    }

    // fragment read bases (row stride 128B; chunk j=kc*4+(l>>4), stored j^(l&7))
    int c0 = ((l >> 4) ^ (l & 7)) * 16;
    int c1 = ((4 + (l >> 4)) ^ (l & 7)) * 16;
    const int arow = wr * 16384 + (l & 15) * 128;
    const int brow = 65536 + (wc >> 1) * 16384 + ((wc & 1) * 64 + (l & 15)) * 128;

#define LDA(CB, M, KC) (*(const bf16x8*)(lds + (CB) + arow + (M) * 2048 + ((KC) ? c1 : c0)))
#define LDB(CB, N, KC) (*(const bf16x8*)(lds + (CB) + brow + (N) * 2048 + ((KC) ? c1 : c0)))
#define STG_A(T, H, CB) do { int kq_ = (T); if (kq_ > NKTm1) kq_ = NKTm1; \
    size_t so_ = (size_t)kq_ * 64; \
    gld_lds16(aS[(H)*2+0] + so_, lds + (CB) + (H) * 16384 + tid * 16); \
    gld_lds16(aS[(H)*2+1] + so_, lds + (CB) + (H) * 16384 + 8192 + tid * 16); } while(0)
#define STG_B(T, H, CB) do { int kq_ = (T); if (kq_ > NKTm1) kq_ = NKTm1; \
    size_t so_ = (size_t)kq_ * 64; \
    gld_lds16(bS[(H)*2+0] + so_, lds + 65536 + (CB) + (H) * 16384 + tid * 16); \
    gld_lds16(bS[(H)*2+1] + so_, lds + 65536 + (CB) + (H) * 16384 + 8192 + tid * 16); } while(0)
#define MF(A, B, C) __builtin_amdgcn_mfma_f32_16x16x32_bf16(A, B, C, 0, 0, 0)
// quadrant Q: m-pair {2Q, 2Q+1}; kc0 pass (8 indep) then kc1 pass (chains of 2)
#define MMQ(Q, X00, X01, X10, X11) do { \
    acc[2*(Q)  ][0] = MF(X00, bv00, acc[2*(Q)  ][0]); \
    acc[2*(Q)  ][1] = MF(X00, bv10, acc[2*(Q)  ][1]); \
    acc[2*(Q)  ][2] = MF(X00, bv20, acc[2*(Q)  ][2]); \
    acc[2*(Q)  ][3] = MF(X00, bv30, acc[2*(Q)  ][3]); \
    acc[2*(Q)+1][0] = MF(X10, bv00, acc[2*(Q)+1][0]); \
    acc[2*(Q)+1][1] = MF(X10, bv10, acc[2*(Q)+1][1]); \
    acc[2*(Q)+1][2] = MF(X10, bv20, acc[2*(Q)+1][2]); \
    acc[2*(Q)+1][3] = MF(X10, bv30, acc[2*(Q)+1][3]); \
    acc[2*(Q)  ][0] = MF(X01, bv01, acc[2*(Q)  ][0]); \
    acc[2*(Q)  ][1] = MF(X01, bv11, acc[2*(Q)  ][1]); \
    acc[2*(Q)  ][2] = MF(X01, bv21, acc[2*(Q)  ][2]); \
    acc[2*(Q)  ][3] = MF(X01, bv31, acc[2*(Q)  ][3]); \
    acc[2*(Q)+1][0] = MF(X11, bv01, acc[2*(Q)+1][0]); \
    acc[2*(Q)+1][1] = MF(X11, bv11, acc[2*(Q)+1][1]); \
    acc[2*(Q)+1][2] = MF(X11, bv21, acc[2*(Q)+1][2]); \
    acc[2*(Q)+1][3] = MF(X11, bv31, acc[2*(Q)+1][3]); } while(0)
// phase: a-frag reads + B-frag reads (P0 only, via __VA_ARGS__ ordering) + stages,
// then barrier / lgkm(0) / prio-wrapped MFMA / (optional vmcnt) / barrier
#define PHASE(CB, Q, VMW, ...) do { \
    bf16x8 x00 = LDA(CB, 2*(Q), 0), x01 = LDA(CB, 2*(Q), 1); \
    bf16x8 x10 = LDA(CB, 2*(Q)+1, 0), x11 = LDA(CB, 2*(Q)+1, 1); \
    __VA_ARGS__; \
    __builtin_amdgcn_s_barrier(); \
    asm volatile("s_waitcnt lgkmcnt(0)" ::: "memory"); \
    __builtin_amdgcn_s_setprio(1); \
    MMQ(Q, x00, x01, x10, x11); \
    __builtin_amdgcn_s_setprio(0); \
    VMW; \
    __builtin_amdgcn_s_barrier(); } while(0)
#define NOWAIT
#define VM4 asm volatile("s_waitcnt vmcnt(4)" ::: "memory")
#define TILE(T, CB, CBo) do { \
    PHASE(CB, 0, NOWAIT, \
        bv00 = LDB(CB,0,0); bv01 = LDB(CB,0,1); bv10 = LDB(CB,1,0); bv11 = LDB(CB,1,1); \
        bv20 = LDB(CB,2,0); bv21 = LDB(CB,2,1); bv30 = LDB(CB,3,0); bv31 = LDB(CB,3,1); \
        STG_A((T)+1, 0, CBo)); \
    PHASE(CB, 1, NOWAIT, STG_A((T)+1, 1, CBo); STG_B((T)+2, 0, CB)); \
    PHASE(CB, 2, NOWAIT, STG_B((T)+2, 1, CB)); \
    PHASE(CB, 3, VM4, ); } while(0)

    f32x4 acc[8][4] = {};
    bf16x8 bv00, bv01, bv10, bv11, bv20, bv21, bv30, bv31;

    // prologue: tile0 (B,B,A,A -> buf0) + B halves of tile1 (-> buf1); retire tile0
    STG_B(0, 0, 0);     STG_B(0, 1, 0);
    STG_A(0, 0, 0);     STG_A(0, 1, 0);
    STG_B(1, 0, 32768); STG_B(1, 1, 32768);
    asm volatile("s_waitcnt vmcnt(4)" ::: "memory");
    __builtin_amdgcn_s_barrier();

    #pragma unroll 1
    for (int kt = 0; kt < NKT; kt += 2){
        TILE(kt,     0,     32768);
        TILE(kt + 1, 32768, 0);
    }

    // epilogue: C/D layout col = lane&15 (+16*n), row = (lane>>4)*4 + reg (+16*M)
    float bs[4];
    #pragma unroll
    for (int n = 0; n < 4; ++n)
        bs[n] = bias[e * NT + n0 + wc * 64 + n * 16 + (l & 15)];
    #pragma unroll
    for (int M = 0; M < 8; ++M){
        #pragma unroll
        for (int r = 0; r < 4; ++r){
            int row = wr * 128 + M * 16 + (l >> 4) * 4 + r;
            int gg = m0 + row;
            if (gg < cnt){
                if (PH1){
                    #pragma unroll
                    for (int n = 0; n < 4; ++n){
                        int col = n0 + wc * 64 + n * 16 + (l & 15);
                        float v = acc[M][n][r] + bs[n];
                        A1out[(size_t)(pb + gg) * FFZ + col] = f2bf(gelu_f(v));
                    }
                } else {
                    int tok = list[e * NTOK + gg];
                    float sc = 0.5f * tprob[tok];
                    #pragma unroll
                    for (int n = 0; n < 4; ++n){
                        int col = n0 + wc * 64 + n * 16 + (l & 15);
                        float v = acc[M][n][r] + bs[n];
                        size_t o = (size_t)tok * HDIM + col;
                        outp[o] = hres[o] + sc * v;
                    }
                }
            }
        }
    }
#undef LDA
#undef LDB
#undef STG_A
#undef STG_B
#undef MF
#undef MMQ
#undef PHASE
#undef NOWAIT
#undef VM4
#undef TILE
}

// ---------------- final: lb_loss ----------------
__global__ void k_final(const float* __restrict__ imp_part, const int* __restrict__ cnt,
                        float* __restrict__ outp){
    __shared__ float imp_s[4];
    int tid = threadIdx.x;
    if (tid < 4){
        float s = 0.f;
        for (int b = 0; b < 256; ++b) s += imp_part[b*4 + tid];
        imp_s[tid] = s;
    }
    __syncthreads();
    if (tid == 0){
        float lb = 0.f;
        #pragma unroll
        for (int e = 0; e < 4; ++e) lb += imp_s[e] * (float)cnt[e];
        outp[(size_t)NTOK * HDIM] = (float)NEXP * lb / ((float)NTOK * (float)NTOK + 1e-8f);
    }
}

extern "C" void kernel_launch(void* const* d_in, const int* in_sizes, int n_in,
                              void* d_out, int out_size, void* d_ws, size_t ws_size,
                              hipStream_t stream){
    const float* h       = (const float*)d_in[0];
    const float* tok_emb = (const float*)d_in[1];
    const float* ln_g = (const float*)d_in[3];
    const float* ln_b = (const float*)d_in[4];
    const float* Wg   = (const float*)d_in[5];
    const float* bg   = (const float*)d_in[6];
    const float* Wf   = (const float*)d_in[7];
    const float* bfv  = (const float*)d_in[8];
    const float* Wr   = (const float*)d_in[9];
    const float* br   = (const float*)d_in[10];
    const float* W1   = (const float*)d_in[11];
    const float* b1   = (const float*)d_in[12];
    const float* W2   = (const float*)d_in[13];
    const float* b2   = (const float*)d_in[14];
    float* outp = (float*)d_out;
    char* ws = (char*)d_ws;

    unsigned short* Ap   = (unsigned short*)(ws);               // 33554432 B  packed h rows (bf16)
    unsigned short* W1T  = (unsigned short*)(ws + 33554432);    // 16777216 B  [E][FFZ][HDIM]
    unsigned short* W2T  = (unsigned short*)(ws + 50331648);    // 16777216 B  [E][HDIM][FFZ]
    unsigned short* A1   = (unsigned short*)(ws + 67108864);    // 67108864 B  packed [NTOK][FFZ]
    float* mu_g  = (float*)(ws + 134217728);
    float* rs_g  = (float*)(ws + 134283264);
    float* tprob = (float*)(ws + 134348800);
    int*   list  = (int*)(ws + 134414336);                      // [E][NTOK]
    int*   cnt   = (int*)(ws + 134676480);                      // [E]
    float* imp   = (float*)(ws + 134676736);                    // [256][E]

    hipMemsetAsync(cnt, 0, NEXP * sizeof(int), stream);
    k_stats<<<NTOK/4, 256, 0, stream>>>(h, mu_g, rs_g);
    k_transpose_bf<<<dim3(FFZ/32, HDIM/32, NEXP), dim3(32,8), 0, stream>>>(W1, W1T, HDIM, FFZ);
    k_transpose_bf<<<dim3(HDIM/32, FFZ/32, NEXP), dim3(32,8), 0, stream>>>(W2, W2T, FFZ, HDIM);
    k_route<<<NTOK/64, 256, 0, stream>>>(h, tok_emb, ln_g, ln_b, Wg, bg, Wf, bfv, Wr, br,
                                         mu_g, rs_g, tprob, list, cnt, imp);
    k_pack<<<NTOK/4, 256, 0, stream>>>(h, list, cnt, Ap);
    k_gemm256<HDIM, FFZ, true><<<dim3(FFZ/256, NTOK/256, NEXP), 512, 0, stream>>>(
        Ap, W1T, list, cnt, b1, A1, nullptr, nullptr, nullptr);
    k_gemm256<FFZ, HDIM, false><<<dim3(HDIM/256, NTOK/256, NEXP), 512, 0, stream>>>(
        A1, W2T, list, cnt, b2, nullptr, h, tprob, outp);
    k_final<<<1, 64, 0, stream>>>(imp, cnt, outp);
}

// Round 8
// 383.185 us; speedup vs baseline: 1.0331x; 1.0331x over previous
//
#include <hip/hip_runtime.h>
#include <hip/hip_bf16.h>
#include <math.h>

#define NTOK 16384
#define HDIM 1024
#define DSZ 32
#define DGZ 32
#define FMZ 64
#define NEXP 4
#define FFZ 2048

typedef __attribute__((ext_vector_type(4))) float f32x4;
typedef __attribute__((ext_vector_type(8))) short bf16x8;

__device__ __forceinline__ unsigned short f2bf(float f){
    union { float f; unsigned int u; } v; v.f = f;
    unsigned int r = (v.u + 0x7FFFu + ((v.u >> 16) & 1u)) >> 16;
    return (unsigned short)r;
}
__device__ __forceinline__ float gelu_f(float x){
    return 0.5f * x * (1.0f + erff(x * 0.70710678118654752440f));
}
__device__ __forceinline__ void gld_lds16(const void* g, void* s){
    __builtin_amdgcn_global_load_lds((const __attribute__((address_space(1))) unsigned int*)g,
                                     (__attribute__((address_space(3))) unsigned int*)s, 16, 0, 0);
}

// ---------------- kernel 1: per-token LN stats only ----------------
__global__ __launch_bounds__(256) void k_stats(const float* __restrict__ h,
        float* __restrict__ mu_g, float* __restrict__ rs_g){
    int tid = threadIdx.x;
    int wv = tid >> 6, l = tid & 63;
    int tok = blockIdx.x * 4 + wv;
    const float4* hp = (const float4*)(h + (size_t)tok * HDIM);
    float s = 0.f, s2 = 0.f;
    #pragma unroll
    for (int p = 0; p < 4; ++p){
        float4 v = hp[p * 64 + l];
        s  += v.x + v.y + v.z + v.w;
        s2 += v.x*v.x + v.y*v.y + v.z*v.z + v.w*v.w;
    }
    #pragma unroll
    for (int off = 32; off >= 1; off >>= 1){
        s  += __shfl_xor(s,  off, 64);
        s2 += __shfl_xor(s2, off, 64);
    }
    if (l == 0){
        float mu = s * (1.0f / HDIM);
        float var = s2 * (1.0f / HDIM) - mu * mu;
        var = fmaxf(var, 0.f);
        mu_g[tok] = mu;
        rs_g[tok] = 1.0f / sqrtf(var + 1e-5f);
    }
}

// ---------------- kernel 2: transpose + fp32->bf16 (weights, per expert) ----------------
__global__ __launch_bounds__(256) void k_transpose_bf(const float* __restrict__ in,
        unsigned short* __restrict__ out, int R, int C){
    __shared__ float tile[32][33];
    size_t mat = (size_t)blockIdx.z * R * C;
    int bx = blockIdx.x * 32;   // col base
    int by = blockIdx.y * 32;   // row base
    int x = threadIdx.x, y = threadIdx.y;
    const float* ip = in + mat;
    unsigned short* op = out + mat;
    #pragma unroll
    for (int i = 0; i < 32; i += 8)
        tile[y + i][x] = ip[(size_t)(by + y + i) * C + (bx + x)];
    __syncthreads();
    #pragma unroll
    for (int i = 0; i < 32; i += 8)
        op[(size_t)(bx + y + i) * R + (by + x)] = f2bf(tile[x][y + i]);
}

// ---------------- kernel 3: fused fp32 routing (unchanged, verified) ----------------
__global__ __launch_bounds__(256) void k_route(
    const float* __restrict__ h, const float* __restrict__ tok_emb,
    const float* __restrict__ ln_g, const float* __restrict__ ln_b,
    const float* __restrict__ Wg, const float* __restrict__ bg,
    const float* __restrict__ Wf, const float* __restrict__ bfv,
    const float* __restrict__ Wr, const float* __restrict__ br,
    const float* __restrict__ mu_g, const float* __restrict__ rs_g,
    float* __restrict__ tprob, int* __restrict__ list, int* __restrict__ cnt,
    float* __restrict__ imp_part)
{
    __shared__ __align__(16) char smem[62208];
    float* lgs  = (float*)(smem);                      // [1024]
    float* lbs  = (float*)(smem + 4096);               // [1024]
    float (*hsT)[64]  = (float(*)[64])(smem + 8192);   // [64 k][64 tok]
    float (*wgs)[32]  = (float(*)[32])(smem + 24576);  // [64 k][32 c]
    float (*gacc)[32] = (float(*)[32])(smem + 32768);  // [64 tok][32 c]
    float* mus = (float*)(smem + 40960);               // [64]
    float* rss = (float*)(smem + 41216);               // [64]
    float (*wrs)[4]     = (float(*)[4])(smem + 41472); // [64][4]
    float (*logit_s)[5] = (float(*)[5])(smem + 42496);
    float (*prob_s)[5]  = (float(*)[5])(smem + 43776);
    int* lcnt  = (int*)(smem + 45056);
    int* lbase = (int*)(smem + 45072);
    float (*agT)[64] = (float(*)[64])(smem);           // [64 j][64 tok]
    float (*wfs)[64] = (float(*)[64])(smem + 16384);   // [64 k][64 f]
    float (*uT)[64]  = (float(*)[64])(smem + 45824);   // [64 f][64 tok]

    int tid = threadIdx.x;
    int t0 = blockIdx.x * 64;

    ((float4*)lgs)[tid] = ((const float4*)ln_g)[tid];
    ((float4*)lbs)[tid] = ((const float4*)ln_b)[tid];
    if (tid < 64){ mus[tid] = mu_g[t0 + tid]; rss[tid] = rs_g[t0 + tid]; }
    if (tid < 64) ((float4*)wrs)[tid] = ((const float4*)Wr)[tid];
    if (tid < 4) lcnt[tid] = 0;
    __syncthreads();

    int l = tid & 63, w = tid >> 6;
    int tg = l & 7, cg = l >> 3, q = w;
    float g_[8][4];
    #pragma unroll
    for (int i=0;i<8;++i){ g_[i][0]=0.f; g_[i][1]=0.f; g_[i][2]=0.f; g_[i][3]=0.f; }
    int tokrow = tid >> 2;
    float m_ = mus[tokrow], r_ = rss[tokrow];
    const float* hrow = h + (size_t)(t0 + tokrow) * HDIM;

    for (int k0 = 0; k0 < HDIM; k0 += 64){
        #pragma unroll
        for (int p = 0; p < 4; ++p){
            int f4 = (tid & 3) + 4 * p;
            float4 v = ((const float4*)(hrow + k0))[f4];
            int c = f4 * 4;
            hsT[c+0][tokrow] = (v.x - m_) * r_ * lgs[k0+c+0] + lbs[k0+c+0];
            hsT[c+1][tokrow] = (v.y - m_) * r_ * lgs[k0+c+1] + lbs[k0+c+1];
            hsT[c+2][tokrow] = (v.z - m_) * r_ * lgs[k0+c+2] + lbs[k0+c+2];
            hsT[c+3][tokrow] = (v.w - m_) * r_ * lgs[k0+c+3] + lbs[k0+c+3];
        }
        {
            int wgrow = tid >> 2;
            #pragma unroll
            for (int p = 0; p < 2; ++p){
                int f4 = (tid & 3) + 4 * p;
                ((float4*)wgs[wgrow])[f4] = ((const float4*)(Wg + (size_t)(k0 + wgrow) * DGZ))[f4];
            }
        }
        __syncthreads();
        #pragma unroll
        for (int kk16 = 0; kk16 < 16; ++kk16){
            int kk = q * 16 + kk16;
            float4 a0 = ((float4*)hsT[kk])[tg*2];
            float4 a1 = ((float4*)hsT[kk])[tg*2+1];
            float4 wv = ((float4*)wgs[kk])[cg];
            float av[8] = {a0.x,a0.y,a0.z,a0.w,a1.x,a1.y,a1.z,a1.w};
            float wj[4] = {wv.x,wv.y,wv.z,wv.w};
            #pragma unroll
            for (int i=0;i<8;++i){
                g_[i][0] += av[i]*wj[0]; g_[i][1] += av[i]*wj[1];
                g_[i][2] += av[i]*wj[2]; g_[i][3] += av[i]*wj[3];
            }
        }
        __syncthreads();
    }
    for (int qq = 0; qq < 4; ++qq){
        if (w == qq){
            #pragma unroll
            for (int i=0;i<8;++i){
                int tok = tg*8+i;
                #pragma unroll
                for (int j=0;j<4;++j){
                    int c = cg*4+j;
                    if (qq == 0) gacc[tok][c] = g_[i][j];
                    else gacc[tok][c] += g_[i][j];
                }
            }
        }
        __syncthreads();
    }
    {
        int tokr = tid >> 2;
        #pragma unroll
        for (int p = 0; p < 2; ++p){
            int f4 = (tid & 3) + 4*p;
            float4 v = ((const float4*)(tok_emb + (size_t)(t0 + tokr) * DSZ))[f4];
            int j = f4 * 4;
            agT[j+0][tokr] = v.x; agT[j+1][tokr] = v.y;
            agT[j+2][tokr] = v.z; agT[j+3][tokr] = v.w;
        }
        int c = tid & 31, tok8 = (tid >> 5) * 8;
        float bgc = bg[c];
        #pragma unroll
        for (int i=0;i<8;++i){
            int tok = tok8 + i;
            agT[32 + c][tok] = gelu_f(gacc[tok][c] + bgc);
        }
        int row = tid >> 2;
        #pragma unroll
        for (int p = 0; p < 4; ++p){
            int f4 = (tid & 3) + 4*p;
            ((float4*)wfs[row])[f4] = ((const float4*)(Wf + (size_t)row * FMZ))[f4];
        }
    }
    __syncthreads();
    {
        int tok = tid & 63, fq = tid >> 6;
        float u_[16];
        #pragma unroll
        for (int i=0;i<16;++i) u_[i]=0.f;
        for (int j = 0; j < 64; ++j){
            float a = agT[j][tok];
            float wv[16];
            *(float4*)&wv[0]  = ((float4*)wfs[j])[fq*4+0];
            *(float4*)&wv[4]  = ((float4*)wfs[j])[fq*4+1];
            *(float4*)&wv[8]  = ((float4*)wfs[j])[fq*4+2];
            *(float4*)&wv[12] = ((float4*)wfs[j])[fq*4+3];
            #pragma unroll
            for (int i=0;i<16;++i) u_[i] += a * wv[i];
        }
        #pragma unroll
        for (int i=0;i<16;++i){
            int f = fq*16+i;
            uT[f][tok] = gelu_f(u_[i] + bfv[f]);
        }
    }
    __syncthreads();
    {
        int tok = tid & 63, e = tid >> 6;
        float lt = 0.f;
        #pragma unroll 8
        for (int f = 0; f < 64; ++f) lt += uT[f][tok] * wrs[f][e];
        logit_s[tok][e] = lt + br[e];
    }
    __syncthreads();
    int my_e = 0, my_pos = 0;
    if (tid < 64){
        int tok = tid;
        float l0 = logit_s[tok][0], l1 = logit_s[tok][1];
        float l2 = logit_s[tok][2], l3 = logit_s[tok][3];
        float mx = fmaxf(fmaxf(l0,l1), fmaxf(l2,l3));
        float p0 = expf(l0-mx), p1 = expf(l1-mx), p2 = expf(l2-mx), p3 = expf(l3-mx);
        float inv = 1.0f / (p0+p1+p2+p3);
        int be = 0; float bp = p0;
        if (p1 > bp){ bp = p1; be = 1; }
        if (p2 > bp){ bp = p2; be = 2; }
        if (p3 > bp){ bp = p3; be = 3; }
        tprob[t0 + tok] = bp * inv;
        prob_s[tok][0] = p0*inv; prob_s[tok][1] = p1*inv;
        prob_s[tok][2] = p2*inv; prob_s[tok][3] = p3*inv;
        my_e = be;
        my_pos = atomicAdd(&lcnt[be], 1);
    }
    __syncthreads();
    if (tid < 4) lbase[tid] = atomicAdd(&cnt[tid], lcnt[tid]);
    __syncthreads();
    if (tid < 64) list[my_e * NTOK + lbase[my_e] + my_pos] = t0 + tid;
    if (tid < 4){
        float s = 0.f;
        for (int t = 0; t < 64; ++t) s += prob_s[t][tid];
        imp_part[blockIdx.x * 4 + tid] = s;
    }
}

// ---------------- kernel 3b: pack h rows into routing order (fp32 -> bf16) ----------------
__global__ __launch_bounds__(256) void k_pack(const float* __restrict__ h,
        const int* __restrict__ list, const int* __restrict__ cnt,
        unsigned short* __restrict__ Ap){
    int wv = threadIdx.x >> 6, l = threadIdx.x & 63;
    int p = blockIdx.x * 4 + wv;
    int b1 = cnt[0], b2 = b1 + cnt[1], b3 = b2 + cnt[2];
    int e, g;
    if (p < b1){ e = 0; g = p; }
    else if (p < b2){ e = 1; g = p - b1; }
    else if (p < b3){ e = 2; g = p - b2; }
    else { e = 3; g = p - b3; }
    int tok = list[e * NTOK + g];
    const float4* src = (const float4*)(h + (size_t)tok * HDIM);
    ushort4* dst = (ushort4*)(Ap + (size_t)p * HDIM);
    #pragma unroll
    for (int i = 0; i < 4; ++i){
        float4 v = src[l + 64 * i];
        ushort4 o; o.x = f2bf(v.x); o.y = f2bf(v.y); o.z = f2bf(v.z); o.w = f2bf(v.w);
        dst[l + 64 * i] = o;
    }
}

// ---------------- grouped GEMM v6: m97-faithful 128x128, BK=32, single-buffer ----------------
// 256 thr = 4 waves (2M x 2N), per-wave C = 64x64 = 4x4 frags of 16x16.
// LDS 16 KiB (As 8KB + Bs 8KB), SINGLE buffer, plain __syncthreads() discipline:
//   per K-step: 4 gld_lds16 (stage) | sync | 8 ds_read_b128 + 16 MFMA | sync.
// NO inline-asm waitcnt: hipcc inserts fine-grained lgkmcnt for ds_read->MFMA and
// drains vmcnt before the barrier (m97's verified schedule). Latency hidden by
// ~3 co-resident blocks/CU (TLP, m114) -- grids are 2048/1024 active blocks.
// Swizzle: row r (64B = 4 chunks of 16B) stores global chunk c at c ^ s(r),
//   s(r) = (r&3)^((r>>2)&3) (Latin square -> 2-way banks = free). Source is
//   pre-swizzled (gld_lds dest stays linear, rule #21); reads XOR the chunk.
template<int KTD, int NT, bool PH1>
__global__ __launch_bounds__(256) void k_gemm(
    const unsigned short* __restrict__ Abase,
    const unsigned short* __restrict__ Bbase,
    const int* __restrict__ list, const int* __restrict__ cnt_g,
    const float* __restrict__ bias,
    unsigned short* __restrict__ A1out,
    const float* __restrict__ hres,
    const float* __restrict__ tprob,
    float* __restrict__ outp)
{
    __shared__ __align__(16) unsigned short As[128 * 32];
    __shared__ __align__(16) unsigned short Bs[128 * 32];
    int e = blockIdx.z;
    int cnt = cnt_g[e];
    int m0 = blockIdx.y * 128;
    if (m0 >= cnt) return;
    int pb = 0;
    #pragma unroll
    for (int i = 0; i < 3; ++i) if (i < e) pb += cnt_g[i];
    int n0 = blockIdx.x * 128;
    int tid = threadIdx.x, w = tid >> 6, l = tid & 63;
    int wr = w >> 1, wc = w & 1;

    // staging: instr j (j=0,1): LDS dest = j*4096 + tid*16 -> row=(j*256+tid)>>2, p=(tid&3)
    // source chunk = p ^ s(row); s(row) depends on row&15 = ((tid>>2)&15) (same for j=0,1)
    int r15 = (tid >> 2) & 15;
    int sv = (r15 & 3) ^ ((r15 >> 2) & 3);
    int srcch = ((tid & 3) ^ sv) * 8;          // element offset of pre-swizzled 16B chunk
    int row0 = tid >> 2, row1 = 64 + (tid >> 2);
    int ga0 = m0 + row0; if (ga0 > cnt - 1) ga0 = cnt - 1;
    int ga1 = m0 + row1; if (ga1 > cnt - 1) ga1 = cnt - 1;
    const unsigned short* aS0 = Abase + (size_t)(pb + ga0) * KTD + srcch;
    const unsigned short* aS1 = Abase + (size_t)(pb + ga1) * KTD + srcch;
    const unsigned short* bS0 = Bbase + ((size_t)e * NT + n0 + row0) * KTD + srcch;
    const unsigned short* bS1 = Bbase + ((size_t)e * NT + n0 + row1) * KTD + srcch;

    // fragment reads: frag row = base + (l&15); k-chunk j = l>>4; read chunk j ^ s(l&15)
    int rs = (l & 3) ^ ((l >> 2) & 3);
    int rdch = ((l >> 4) ^ rs) * 16;           // byte offset within row
    int arow = (wr * 64 + (l & 15)) * 64 + rdch;   // + m*16*64
    int brow = (wc * 64 + (l & 15)) * 64 + rdch;   // + n*16*64

    f32x4 acc[4][4] = {};

    #pragma unroll 1
    for (int k0 = 0; k0 < KTD; k0 += 32){
        gld_lds16(aS0 + k0, (char*)As + tid * 16);
        gld_lds16(aS1 + k0, (char*)As + 4096 + tid * 16);
        gld_lds16(bS0 + k0, (char*)Bs + tid * 16);
        gld_lds16(bS1 + k0, (char*)Bs + 4096 + tid * 16);
        __syncthreads();
        bf16x8 a[4], b[4];
        #pragma unroll
        for (int m = 0; m < 4; ++m) a[m] = *(const bf16x8*)((const char*)As + arow + m * 1024);
        #pragma unroll
        for (int n = 0; n < 4; ++n) b[n] = *(const bf16x8*)((const char*)Bs + brow + n * 1024);
        #pragma unroll
        for (int m = 0; m < 4; ++m)
            #pragma unroll
            for (int n = 0; n < 4; ++n)
                acc[m][n] = __builtin_amdgcn_mfma_f32_16x16x32_bf16(a[m], b[n], acc[m][n], 0, 0, 0);
        __syncthreads();
    }

    // epilogue: C/D layout col = lane&15 (+16*n), row = (lane>>4)*4 + reg (+16*m)
    float bs[4];
    #pragma unroll
    for (int n = 0; n < 4; ++n)
        bs[n] = bias[e * NT + n0 + wc * 64 + n * 16 + (l & 15)];
    #pragma unroll
    for (int m = 0; m < 4; ++m){
        #pragma unroll
        for (int r = 0; r < 4; ++r){
            int row = wr * 64 + m * 16 + (l >> 4) * 4 + r;
            int g = m0 + row;
            if (g < cnt){
                if (PH1){
                    #pragma unroll
                    for (int n = 0; n < 4; ++n){
                        int col = n0 + wc * 64 + n * 16 + (l & 15);
                        float v = acc[m][n][r] + bs[n];
                        A1out[(size_t)(pb + g) * FFZ + col] = f2bf(gelu_f(v));
                    }
                } else {
                    int tok = list[e * NTOK + g];
                    float sc = 0.5f * tprob[tok];
                    #pragma unroll
                    for (int n = 0; n < 4; ++n){
                        int col = n0 + wc * 64 + n * 16 + (l & 15);
                        float v = acc[m][n][r] + bs[n];
                        size_t o = (size_t)tok * HDIM + col;
                        outp[o] = hres[o] + sc * v;
                    }
                }
            }
        }
    }
}

// ---------------- final: lb_loss ----------------
__global__ void k_final(const float* __restrict__ imp_part, const int* __restrict__ cnt,
                        float* __restrict__ outp){
    __shared__ float imp_s[4];
    int tid = threadIdx.x;
    if (tid < 4){
        float s = 0.f;
        for (int b = 0; b < 256; ++b) s += imp_part[b*4 + tid];
        imp_s[tid] = s;
    }
    __syncthreads();
    if (tid == 0){
        float lb = 0.f;
        #pragma unroll
        for (int e = 0; e < 4; ++e) lb += imp_s[e] * (float)cnt[e];
        outp[(size_t)NTOK * HDIM] = (float)NEXP * lb / ((float)NTOK * (float)NTOK + 1e-8f);
    }
}

extern "C" void kernel_launch(void* const* d_in, const int* in_sizes, int n_in,
                              void* d_out, int out_size, void* d_ws, size_t ws_size,
                              hipStream_t stream){
    const float* h       = (const float*)d_in[0];
    const float* tok_emb = (const float*)d_in[1];
    const float* ln_g = (const float*)d_in[3];
    const float* ln_b = (const float*)d_in[4];
    const float* Wg   = (const float*)d_in[5];
    const float* bg   = (const float*)d_in[6];
    const float* Wf   = (const float*)d_in[7];
    const float* bfv  = (const float*)d_in[8];
    const float* Wr   = (const float*)d_in[9];
    const float* br   = (const float*)d_in[10];
    const float* W1   = (const float*)d_in[11];
    const float* b1   = (const float*)d_in[12];
    const float* W2   = (const float*)d_in[13];
    const float* b2   = (const float*)d_in[14];
    float* outp = (float*)d_out;
    char* ws = (char*)d_ws;

    unsigned short* Ap   = (unsigned short*)(ws);               // 33554432 B  packed h rows (bf16)
    unsigned short* W1T  = (unsigned short*)(ws + 33554432);    // 16777216 B  [E][FFZ][HDIM]
    unsigned short* W2T  = (unsigned short*)(ws + 50331648);    // 16777216 B  [E][HDIM][FFZ]
    unsigned short* A1   = (unsigned short*)(ws + 67108864);    // 67108864 B  packed [NTOK][FFZ]
    float* mu_g  = (float*)(ws + 134217728);
    float* rs_g  = (float*)(ws + 134283264);
    float* tprob = (float*)(ws + 134348800);
    int*   list  = (int*)(ws + 134414336);                      // [E][NTOK]
    int*   cnt   = (int*)(ws + 134676480);                      // [E]
    float* imp   = (float*)(ws + 134676736);                    // [256][E]

    hipMemsetAsync(cnt, 0, NEXP * sizeof(int), stream);
    k_stats<<<NTOK/4, 256, 0, stream>>>(h, mu_g, rs_g);
    k_transpose_bf<<<dim3(FFZ/32, HDIM/32, NEXP), dim3(32,8), 0, stream>>>(W1, W1T, HDIM, FFZ);
    k_transpose_bf<<<dim3(HDIM/32, FFZ/32, NEXP), dim3(32,8), 0, stream>>>(W2, W2T, FFZ, HDIM);
    k_route<<<NTOK/64, 256, 0, stream>>>(h, tok_emb, ln_g, ln_b, Wg, bg, Wf, bfv, Wr, br,
                                         mu_g, rs_g, tprob, list, cnt, imp);
    k_pack<<<NTOK/4, 256, 0, stream>>>(h, list, cnt, Ap);
    k_gemm<HDIM, FFZ, true><<<dim3(FFZ/128, NTOK/128, NEXP), 256, 0, stream>>>(
        Ap, W1T, list, cnt, b1, A1, nullptr, nullptr, nullptr);
    k_gemm<FFZ, HDIM, false><<<dim3(HDIM/128, NTOK/128, NEXP), 256, 0, stream>>>(
        A1, W2T, list, cnt, b2, nullptr, h, tprob, outp);
    k_final<<<1, 64, 0, stream>>>(imp, cnt, outp);
}